// Round 11
// baseline (121.153 us; speedup 1.0000x reference)
//
#include <hip/hip_runtime.h>

// VQ-VAE codebook lookup via bf16 MFMA + rigorous exact re-check.
// z_e [65536,64] f32, codebook [1024,64] f32.
// Out = concat(z_q [65536*64] f32, indices [65536] as f32).
//
// score s(n,k) = x.c - 0.5*c2[k] (= -dist/2 up to row-const). Sweep 1
// (MFMA bf16, acc init = -c2/2): per-row max m, merged across waves via
// LDS. Sweep 2: recompute (bit-identical), record codes with
// s >= gmax - DELTA_H; candidate set provably contains the exact argmin
// (DELTA_H = 1.5 >= 2*eps, eps <= 2^-8*||x||*||c|| < 0.5). 1 candidate ->
// done; else exact fp32 re-check, first-occurrence tie-break.
//
// Round-11 geometry: 768-thread blocks (12 waves, 1 block/CU -> 3 waves/
// SIMD at VGPR cap 170 -- fits ~135 live regs, no spill risk), 128 shared
// rows, waves PARTITION the 64 B-tiles (5-6 each) -> B-traffic stays at
// R10's 128 MB while occupancy rises 1.5x. z_e tile converted to bf16 once
// into LDS (stride 72 shorts: 16B-aligned b128, 2-way-free banks), frag-
// loaded by all 12 waves (kills 12x-redundant f2bf VALU).

typedef __attribute__((ext_vector_type(8))) short short8;
typedef __attribute__((ext_vector_type(4))) float f32x4;

#define N_ROWS  65536
#define D       64
#define K_CODES 1024
#define DELTA_H 1.5f
#define CAP     16
#define WAVES   12
#define ZSTRIDE 72   // shorts; 144 B rows: b128-aligned, 2-way banks (free)

#define TILES(F) F(0) F(1) F(2) F(3) F(4) F(5) F(6) F(7)

__device__ __forceinline__ unsigned short f2bf(float f) {
    unsigned u = __builtin_bit_cast(unsigned, f);
    unsigned r = (u + 0x7fffu + ((u >> 16) & 1u)) >> 16;   // RNE
    return (unsigned short)r;
}

__device__ __forceinline__ short8 cvt8(float4 u, float4 v) {
    short8 r;
    r[0] = (short)f2bf(u.x); r[1] = (short)f2bf(u.y);
    r[2] = (short)f2bf(u.z); r[3] = (short)f2bf(u.w);
    r[4] = (short)f2bf(v.x); r[5] = (short)f2bf(v.y);
    r[6] = (short)f2bf(v.z); r[7] = (short)f2bf(v.w);
    return r;
}

__device__ __forceinline__ float dist_f32(const float* __restrict__ xr,
                                          const float* __restrict__ cr,
                                          float c2k) {
    float a = 0.f, b = 0.f, c = 0.f, d = 0.f;
#pragma unroll
    for (int i = 0; i < 16; i += 2) {
        const float4 x0 = ((const float4*)xr)[i];
        const float4 c0 = ((const float4*)cr)[i];
        const float4 x1 = ((const float4*)xr)[i + 1];
        const float4 c1 = ((const float4*)cr)[i + 1];
        a = fmaf(x0.x, c0.x, a); b = fmaf(x0.y, c0.y, b);
        c = fmaf(x0.z, c0.z, c); d = fmaf(x0.w, c0.w, d);
        a = fmaf(x1.x, c1.x, a); b = fmaf(x1.y, c1.y, b);
        c = fmaf(x1.z, c1.z, c); d = fmaf(x1.w, c1.w, d);
    }
    const float dot = (a + b) + (c + d);
    return fmaf(-2.f, dot, c2k);
}

// prep: c2[k] (fp32) + codebook -> bf16. 16 blocks x 256, quarter-row/thread.
__global__ __launch_bounds__(256) void prep_kernel(const float* __restrict__ cb,
                                                   float* __restrict__ c2,
                                                   unsigned short* __restrict__ cbb) {
    const int gt = blockIdx.x * 256 + threadIdx.x;  // 0..4095
    const int c  = gt >> 2;
    const int q  = gt & 3;
    const float* src = cb + (size_t)c * D + q * 16;
    unsigned short* dst = cbb + (size_t)c * D + q * 16;
    float s = 0.f;
#pragma unroll
    for (int i = 0; i < 2; ++i) {
        const float4 u = ((const float4*)src)[2 * i];
        const float4 v = ((const float4*)src)[2 * i + 1];
        s = fmaf(u.x, u.x, s); s = fmaf(u.y, u.y, s);
        s = fmaf(u.z, u.z, s); s = fmaf(u.w, u.w, s);
        s = fmaf(v.x, v.x, s); s = fmaf(v.y, v.y, s);
        s = fmaf(v.z, v.z, s); s = fmaf(v.w, v.w, s);
        *(short8*)(dst + 8 * i) = cvt8(u, v);
    }
    s += __shfl_xor(s, 1);
    s += __shfl_xor(s, 2);
    if (q == 0) c2[c] = s;
}

__global__ __launch_bounds__(768, 3) void vq_kernel(const float* __restrict__ z_e,
                                                    const float* __restrict__ cb,
                                                    const float* __restrict__ c2g,
                                                    const unsigned short* __restrict__ cbb,
                                                    float* __restrict__ out) {
    __shared__ unsigned short zA[128 * ZSTRIDE];   // 18432 B, bf16 A-tile
    __shared__ float qmax_s[WAVES][128];
    __shared__ float gmax_s[128];
    __shared__ int   cnt_s[128];
    __shared__ int   ovf_s[128];
    __shared__ int   win_s[128];
    __shared__ int   cand_s[128][CAP];

    const int tid   = threadIdx.x;
    const int w     = tid >> 6;        // wave 0..11 -> B-tile range
    const int lane  = tid & 63;
    const int lcol  = lane & 15;       // row within A-tile / code within B-tile
    const int lk    = lane >> 4;       // k-group
    const int rbase = blockIdx.x * 128;

    if (tid < 128) { cnt_s[tid] = 0; ovf_s[tid] = 0; }

    // ---- stage z_e tile -> bf16 LDS (once per block, shared by 12 waves) ----
    if (tid < 512) {
        const int row = tid >> 2;
        const int q   = tid & 3;       // 16-float chunk
        const float4* src = (const float4*)(z_e + (size_t)(rbase + row) * D + q * 16);
        unsigned short* dst = zA + row * ZSTRIDE + q * 16;
        *(short8*)(dst)     = cvt8(src[0], src[1]);
        *(short8*)(dst + 8) = cvt8(src[2], src[3]);
    }
    __syncthreads();

    // ---- A fragments from LDS: tile i = rows rbase + 16*i + lcol ----
#define DECLA(i) short8 a0_##i, a1_##i;
    TILES(DECLA)
#define LOADA(i)                                                               \
    {                                                                          \
        const unsigned short* p = zA + (16 * (i) + lcol) * ZSTRIDE + 8 * lk;   \
        a0_##i = *(const short8*)(p);                                          \
        a1_##i = *(const short8*)(p + 32);                                     \
    }
    TILES(LOADA)

    // wave's B-tile range: tt in [sw, ew), global tiles 0..63
    const int sw = (16 * w) / 3;
    const int ew = (16 * (w + 1)) / 3;

    const unsigned short* bp  = cbb + (size_t)lcol * D + 8 * lk;
    const float*          c2p = c2g + lcol;

#define LOADB(T)                                                      \
    bn0 = *(const short8*)(bp + (size_t)(T) * 1024);                  \
    bn1 = *(const short8*)(bp + (size_t)(T) * 1024 + 32);             \
    c2n = c2p[(T) * 16];

    // ---- sweep 1: per-row max score over this wave's tile range ----
#define DECLM(i) float m##i##0 = -3.4e38f, m##i##1 = -3.4e38f,                 \
                       m##i##2 = -3.4e38f, m##i##3 = -3.4e38f;
    TILES(DECLM)
    {
        short8 bc0, bc1, bn0, bn1;
        float c2c, c2n;
        LOADB(sw);
        bc0 = bn0; bc1 = bn1; c2c = c2n;
        for (int tt = sw; tt < ew; ++tt) {
            { const int tn = (tt + 1 < 64) ? tt + 1 : 63; LOADB(tn); }
            {
                const float sv = -0.5f * c2c;
#define DOTILE1(i)                                                                    \
                f32x4 acc##i = {sv, sv, sv, sv};                                      \
                acc##i = __builtin_amdgcn_mfma_f32_16x16x32_bf16(a0_##i, bc0, acc##i, 0, 0, 0); \
                acc##i = __builtin_amdgcn_mfma_f32_16x16x32_bf16(a1_##i, bc1, acc##i, 0, 0, 0); \
                m##i##0 = fmaxf(m##i##0, acc##i[0]);                                  \
                m##i##1 = fmaxf(m##i##1, acc##i[1]);                                  \
                m##i##2 = fmaxf(m##i##2, acc##i[2]);                                  \
                m##i##3 = fmaxf(m##i##3, acc##i[3]);
                TILES(DOTILE1)
            }
            bc0 = bn0; bc1 = bn1; c2c = c2n;
        }
    }

    // reduce maxima over the 16 code-lanes sharing this lk-group
#define REDT(i)                                                       \
    m##i##0 = fmaxf(m##i##0, __shfl_xor(m##i##0, OFF));               \
    m##i##1 = fmaxf(m##i##1, __shfl_xor(m##i##1, OFF));               \
    m##i##2 = fmaxf(m##i##2, __shfl_xor(m##i##2, OFF));               \
    m##i##3 = fmaxf(m##i##3, __shfl_xor(m##i##3, OFF));
    {
#define OFF 1
        TILES(REDT)
#undef OFF
#define OFF 2
        TILES(REDT)
#undef OFF
#define OFF 4
        TILES(REDT)
#undef OFF
#define OFF 8
        TILES(REDT)
#undef OFF
    }

    if (lcol == 0) {
#define WRQ(i)                                                        \
        qmax_s[w][16 * (i) + 4 * lk + 0] = m##i##0;                   \
        qmax_s[w][16 * (i) + 4 * lk + 1] = m##i##1;                   \
        qmax_s[w][16 * (i) + 4 * lk + 2] = m##i##2;                   \
        qmax_s[w][16 * (i) + 4 * lk + 3] = m##i##3;
        TILES(WRQ)
    }
    __syncthreads();
    if (tid < 128) {
        float g = qmax_s[0][tid];
#pragma unroll
        for (int ww = 1; ww < WAVES; ++ww) g = fmaxf(g, qmax_s[ww][tid]);
        gmax_s[tid] = g;
    }
    __syncthreads();

    // per-lane thresholds from GLOBAL maxima (broadcast LDS reads)
#define DECLH(i)                                                      \
    const float h##i##0 = gmax_s[16 * (i) + 4 * lk + 0] - DELTA_H;    \
    const float h##i##1 = gmax_s[16 * (i) + 4 * lk + 1] - DELTA_H;    \
    const float h##i##2 = gmax_s[16 * (i) + 4 * lk + 2] - DELTA_H;    \
    const float h##i##3 = gmax_s[16 * (i) + 4 * lk + 3] - DELTA_H;
    TILES(DECLH)
#define MIN4(i) fminf(fminf(h##i##0, h##i##1), fminf(h##i##2, h##i##3))
    const float gmin = fminf(
        fminf(fminf(MIN4(0), MIN4(1)), fminf(MIN4(2), MIN4(3))),
        fminf(fminf(MIN4(4), MIN4(5)), fminf(MIN4(6), MIN4(7))));

#define REC(RL, CODE)                                                 \
    {                                                                 \
        const int sl = atomicAdd(&cnt_s[RL], 1);                      \
        if (sl < CAP) cand_s[RL][sl] = (CODE); else ovf_s[RL] = 1;    \
    }

    // ---- sweep 2: recompute (bit-identical), record candidates ----
    {
        short8 bc0, bc1, bn0, bn1;
        float c2c, c2n;
        LOADB(sw);
        bc0 = bn0; bc1 = bn1; c2c = c2n;
        for (int tt = sw; tt < ew; ++tt) {
            { const int tn = (tt + 1 < 64) ? tt + 1 : 63; LOADB(tn); }
            {
                const float sv = -0.5f * c2c;
#define DOTILE2(i)                                                                    \
                f32x4 acc##i = {sv, sv, sv, sv};                                      \
                acc##i = __builtin_amdgcn_mfma_f32_16x16x32_bf16(a0_##i, bc0, acc##i, 0, 0, 0); \
                acc##i = __builtin_amdgcn_mfma_f32_16x16x32_bf16(a1_##i, bc1, acc##i, 0, 0, 0);
                TILES(DOTILE2)
#define MAX4(i) fmaxf(fmaxf(acc##i[0], acc##i[1]), fmaxf(acc##i[2], acc##i[3]))
                const float tm = fmaxf(
                    fmaxf(fmaxf(MAX4(0), MAX4(1)), fmaxf(MAX4(2), MAX4(3))),
                    fmaxf(fmaxf(MAX4(4), MAX4(5)), fmaxf(MAX4(6), MAX4(7))));
                if (tm >= gmin) {
                    const int code = (tt << 4) + lcol;
#define CHK(i)                                                            \
                    if (acc##i[0] >= h##i##0) REC(16 * (i) + 4 * lk + 0, code); \
                    if (acc##i[1] >= h##i##1) REC(16 * (i) + 4 * lk + 1, code); \
                    if (acc##i[2] >= h##i##2) REC(16 * (i) + 4 * lk + 2, code); \
                    if (acc##i[3] >= h##i##3) REC(16 * (i) + 4 * lk + 3, code);
                    TILES(CHK)
                }
            }
            bc0 = bn0; bc1 = bn1; c2c = c2n;
        }
    }
    __syncthreads();

    // ---- epilogue: resolve winner per row (exact fp32 when needed) ----
    if (tid < 128) {
        const int grow = rbase + tid;
        const int cnt  = cnt_s[tid];
        int win;
        if (ovf_s[tid] == 0 && cnt == 1) {
            win = cand_s[tid][0];
        } else {
            const float* xr = z_e + (size_t)grow * D;
            float bestd = 3.4e38f;
            int   bi    = K_CODES;
            if (ovf_s[tid]) {
                for (int k = 0; k < K_CODES; ++k) {
                    const float dk = dist_f32(xr, cb + (size_t)k * D, c2g[k]);
                    if (dk < bestd || (dk == bestd && k < bi)) { bestd = dk; bi = k; }
                }
            } else {
                for (int j = 0; j < cnt; ++j) {
                    const int k = cand_s[tid][j];
                    const float dk = dist_f32(xr, cb + (size_t)k * D, c2g[k]);
                    if (dk < bestd || (dk == bestd && k < bi)) { bestd = dk; bi = k; }
                }
            }
            win = bi;
        }
        win_s[tid] = win;
        out[(size_t)N_ROWS * D + grow] = (float)win;
    }
    __syncthreads();

    // ---- z_q gather+write: 4 threads per row, 4 float4 each ----
    if (tid < 512) {
        const int rl   = tid >> 2;
        const int q    = tid & 3;
        const int grow = rbase + rl;
        const float4* src = (const float4*)(cb + (size_t)win_s[rl] * D) + q * 4;
        float4*       dst = (float4*)(out + (size_t)grow * D) + q * 4;
#pragma unroll
        for (int i = 0; i < 4; ++i) dst[i] = src[i];
    }
}

extern "C" void kernel_launch(void* const* d_in, const int* in_sizes, int n_in,
                              void* d_out, int out_size, void* d_ws, size_t ws_size,
                              hipStream_t stream) {
    const float* z_e = (const float*)d_in[0];
    const float* cb  = (const float*)d_in[1];
    float* out = (float*)d_out;
    float*          c2  = (float*)d_ws;                          // 4 KB
    unsigned short* cbb = (unsigned short*)((char*)d_ws + 4096); // 128 KB

    hipLaunchKernelGGL(prep_kernel, dim3(16), dim3(256), 0, stream, cb, c2, cbb);
    hipLaunchKernelGGL(vq_kernel, dim3(N_ROWS / 128), dim3(768), 0, stream,
                       z_e, cb, c2, cbb, out);
}